// Round 3
// baseline (8286.464 us; speedup 1.0000x reference)
//
#include <hip/hip_runtime.h>

#define BB 64
#define TT 4995
#define VV 4096
#define EE 100
#define UU 64
#define U3 192

// embW[v][k] = (emb @ W1 + b1[0])[v][k], 3.07 MB, L2-resident.
__device__ float g_embW[VV * U3];

__device__ __forceinline__ float fast_sigmoid(float x) {
    return __builtin_amdgcn_rcpf(1.0f + __expf(-x));
}
__device__ __forceinline__ float fast_tanh(float x) {
    return __builtin_amdgcn_rcpf(1.0f + __expf(-2.0f * x)) * 2.0f - 1.0f;
}
// Broadcast lane `lane` of v to all lanes (v_readlane -> SGPR, free to FMA).
__device__ __forceinline__ float lane_bcast(float v, int lane) {
    return __int_as_float(__builtin_amdgcn_readlane(__float_as_int(v), lane));
}

__global__ void gru_embw_kernel(const float* __restrict__ emb,
                                const float* __restrict__ W1,
                                const float* __restrict__ b1) {
    __shared__ float row[EE];
    const int v = blockIdx.x;
    const int k = threadIdx.x;  // 0..191
    if (k < EE) row[k] = emb[v * EE + k];
    __syncthreads();
    float acc = b1[k];
    #pragma unroll 4
    for (int j = 0; j < EE; ++j)
        acc = fmaf(row[j], W1[j * U3 + k], acc);
    g_embW[v * U3 + k] = acc;
}

// Fused 2-layer GRU scan. One workgroup (192 thr = 3 waves) per batch element.
// wave 0 -> z gate, wave 1 -> r gate, wave 2 -> candidate (hh) pieces.
// h1/h2 are REPLICATED per wave in registers (hv1/hv2 = h[lane]); dot
// products broadcast h via v_readlane on each wave's own SIMD — zero LDS
// traffic for h, zero cross-wave h distribution (redundant identical update).
__global__ __launch_bounds__(192, 1)
void gru_scan_kernel(const int* __restrict__ tokens,
                     const float* __restrict__ U1,
                     const float* __restrict__ b1,
                     const float* __restrict__ W2,
                     const float* __restrict__ U2,
                     const float* __restrict__ b2,
                     const float* __restrict__ Wout,
                     const float* __restrict__ bout,
                     float* __restrict__ out) {
    const int b = blockIdx.x;
    const int k = threadIdx.x;       // global col 0..191
    const int lane = k & 63;
    const int wave = k >> 6;         // 0=z, 1=r, 2=hh

    __shared__ float g1z[UU], g1r[UU], g1xh[UU], g1hph[UU];
    __shared__ float g2z[UU], g2r[UU], g2xh[UU], g2hph[UU];

    // Weight columns in VGPRs (~192 regs), loaded once (L2-resident).
    float u1c[UU], w2c[UU], u2c[UU];
    #pragma unroll
    for (int j = 0; j < UU; ++j) {
        u1c[j] = U1[j * U3 + k];
        w2c[j] = W2[j * U3 + k];
        u2c[j] = U2[j * U3 + k];
    }
    const float bu1 = b1[U3 + k];   // recurrent bias, layer 1
    const float b20 = b2[k];        // input bias, layer 2
    const float b21 = b2[U3 + k];   // recurrent bias, layer 2

    float hv1 = 0.0f, hv2 = 0.0f;   // h1[lane], h2[lane], replicated per wave

    const int* tokb = tokens + b * TT;
    int tok1 = tokb[1];
    float xk = g_embW[tokb[0] * U3 + k];   // xp1 (input bias folded in)

    #pragma unroll 1
    for (int t = 0; t < TT; ++t) {
        // prefetch: token 2 ahead, embW row 1 ahead (hides L2 latency)
        const int tnn = (t + 2 < TT) ? (t + 2) : (TT - 1);
        const int tok_nn = tokb[tnn];
        const float xk_next = g_embW[tok1 * U3 + k];

        // ---- layer-1 dot: acc = bu1 + sum_j h1[j] * U1[j, k] ----
        float a0 = bu1, a1 = 0.0f;
        #pragma unroll
        for (int j = 0; j < UU; j += 2) {
            a0 = fmaf(lane_bcast(hv1, j),     u1c[j],     a0);
            a1 = fmaf(lane_bcast(hv1, j + 1), u1c[j + 1], a1);
        }
        const float acc = a0 + a1;

        if (wave == 0)      g1z[lane] = fast_sigmoid(xk + acc);
        else if (wave == 1) g1r[lane] = fast_sigmoid(xk + acc);
        else              { g1xh[lane] = xk; g1hph[lane] = acc; }
        __syncthreads();                                   // barrier 1

        // ---- h1 update: all waves redundantly, in-register ----
        {
            const float z  = g1z[lane];
            const float r  = g1r[lane];
            const float xh = g1xh[lane];
            const float hp = g1hph[lane];
            const float hh = fast_tanh(xh + r * hp);
            hv1 = z * hv1 + (1.0f - z) * hh;
        }

        // ---- layer-2 dual dot: c1 = b20 + h1.W2[:,k], c2 = b21 + h2.U2[:,k]
        float c1 = b20, c2 = b21;
        #pragma unroll
        for (int j = 0; j < UU; ++j) {
            c1 = fmaf(lane_bcast(hv1, j), w2c[j], c1);
            c2 = fmaf(lane_bcast(hv2, j), u2c[j], c2);
        }

        if (wave == 0)      g2z[lane] = fast_sigmoid(c1 + c2);
        else if (wave == 1) g2r[lane] = fast_sigmoid(c1 + c2);
        else              { g2xh[lane] = c1; g2hph[lane] = c2; }
        __syncthreads();                                   // barrier 2

        // ---- h2 update: all waves redundantly, in-register ----
        {
            const float z  = g2z[lane];
            const float r  = g2r[lane];
            const float xh = g2xh[lane];
            const float hp = g2hph[lane];
            const float hh = fast_tanh(xh + r * hp);
            hv2 = z * hv2 + (1.0f - z) * hh;
        }

        xk = xk_next;
        tok1 = tok_nn;
    }

    // ---- output head: out[b] = sigmoid(h2 . Wout + bout) ----
    if (wave == 0) {
        float s = bout[0];
        #pragma unroll
        for (int j = 0; j < UU; ++j)
            s = fmaf(lane_bcast(hv2, j), Wout[j], s);
        if (lane == 0) out[b] = fast_sigmoid(s);
    }
}

extern "C" void kernel_launch(void* const* d_in, const int* in_sizes, int n_in,
                              void* d_out, int out_size, void* d_ws, size_t ws_size,
                              hipStream_t stream) {
    const int*   tokens = (const int*)  d_in[0];
    const float* emb    = (const float*)d_in[1];
    const float* W1     = (const float*)d_in[2];
    const float* U1w    = (const float*)d_in[3];
    const float* b1     = (const float*)d_in[4];
    const float* W2     = (const float*)d_in[5];
    const float* U2w    = (const float*)d_in[6];
    const float* b2     = (const float*)d_in[7];
    const float* Wout   = (const float*)d_in[8];
    const float* bout   = (const float*)d_in[9];
    float* out = (float*)d_out;

    gru_embw_kernel<<<VV, 192, 0, stream>>>(emb, W1, b1);
    gru_scan_kernel<<<BB, 192, 0, stream>>>(tokens, U1w, b1, W2, U2w,
                                            b2, Wout, bout, out);
}